// Round 2
// baseline (1066.332 us; speedup 1.0000x reference)
//
#include <hip/hip_runtime.h>

#define LN_EPS 1e-5f
#define RSCALE (1.0f / 30.0f)

typedef short short8  __attribute__((ext_vector_type(8)));
typedef short short4v __attribute__((ext_vector_type(4)));
typedef float f32x4   __attribute__((ext_vector_type(4)));

__device__ __forceinline__ unsigned short f2bf(float f) {
    unsigned u = __builtin_bit_cast(unsigned, f);
    u = u + 0x7FFFu + ((u >> 16) & 1u);   // round-to-nearest-even
    return (unsigned short)(u >> 16);
}

__device__ __forceinline__ float gelu_f(float x) {
    float u  = 0.7978845608028654f * (x + 0.044715f * x * x * x);
    float e  = __expf(-2.0f * fabsf(u));
    float t  = 1.0f - 2.0f * e / (1.0f + e);
    return 0.5f * x * (1.0f + copysignf(t, u));
}

__device__ __forceinline__ short8 cvt8(float4 a, float4 b) {
    short8 r;
    r[0] = (short)f2bf(a.x); r[1] = (short)f2bf(a.y);
    r[2] = (short)f2bf(a.z); r[3] = (short)f2bf(a.w);
    r[4] = (short)f2bf(b.x); r[5] = (short)f2bf(b.y);
    r[6] = (short)f2bf(b.z); r[7] = (short)f2bf(b.w);
    return r;
}

__device__ __forceinline__ f32x4 zero4() {
    f32x4 v; v.x = 0.f; v.y = 0.f; v.z = 0.f; v.w = 0.f; return v;
}

// ---------------------------------------------------------------------------
// Kernel 0: convert W1/W2/W3 (fp32 [in][out]) -> bf16 transposed [out][in]
// ---------------------------------------------------------------------------
__global__ __launch_bounds__(256) void prep_w(
    const float* __restrict__ W1, const float* __restrict__ W2,
    const float* __restrict__ W3,
    unsigned short* __restrict__ w1t, unsigned short* __restrict__ w2t,
    unsigned short* __restrict__ w3t)
{
    int t = blockIdx.x * 256 + threadIdx.x;
    if (t < 65536) {                       // W1: [512][128] -> w1t [128][512]
        int m = t & 127, k = t >> 7;
        w1t[m * 512 + k] = f2bf(W1[k * 128 + m]);
    } else if (t < 81920) {                // W2
        int u = t - 65536, m = u & 127, k = u >> 7;
        w2t[m * 128 + k] = f2bf(W2[k * 128 + m]);
    } else if (t < 98304) {                // W3
        int u = t - 81920, m = u & 127, k = u >> 7;
        w3t[m * 128 + k] = f2bf(W3[k * 128 + m]);
    }
}

// ---------------------------------------------------------------------------
// Kernel 1: wave-autonomous fused edge MLP. 1 wave = 1 node (48 rows,
// 3 N-tiles x 8 M-tiles, 16x16x32 bf16 MFMA). ZERO __syncthreads.
//  - W fragments read directly from global (L2-resident bf16 transposed).
//  - GEMM1 B-fragments read directly from hE/hV (fp32, streaming, each
//    128-B line touched exactly once), 1-deep register prefetch.
//  - H activations round-trip through a per-wave 12 KB LDS slab
//    (XOR-swizzled 16-B blocks) for the C/D -> A/B layout transform;
//    same-wave DS ops are in-order, so no barrier needed.
// ---------------------------------------------------------------------------
__global__ __launch_bounds__(256, 2) void edge_mlp(
    const float* __restrict__ hV, const float* __restrict__ hE,
    const float* __restrict__ mAtt,
    const unsigned short* __restrict__ w1t, const unsigned short* __restrict__ w2t,
    const unsigned short* __restrict__ w3t,
    const float* __restrict__ b1, const float* __restrict__ b2,
    const float* __restrict__ b3, float* __restrict__ dh)
{
    __shared__ short Hs[4][48 * 128];      // per-wave slab: 48 rows x 128 bf16

    const int tid  = threadIdx.x;
    const int wv   = tid >> 6;
    const int lane = tid & 63;
    const int ln   = lane & 15;            // n index within tile / m row
    const int kg   = lane >> 4;            // quad
    const int node = blockIdx.x * 4 + wv;
    short* Hw = &Hs[wv][0];

    f32x4 acc[8][3];

    // ---- phase A: k 0..127 (hV part, identical for all 48 rows) ----
#pragma unroll
    for (int j = 0; j < 8; ++j) acc[j][0] = zero4();
#pragma unroll
    for (int ks = 0; ks < 4; ++ks) {
        const float* hp = hV + node * 128 + ks * 32 + kg * 8;
        float4 v0 = *(const float4*)hp;
        float4 v1 = *(const float4*)(hp + 4);
        short8 bf = cvt8(v0, v1);
#pragma unroll
        for (int j = 0; j < 8; ++j) {
            short8 af = *(const short8*)(w1t + (j * 16 + ln) * 512 + ks * 32 + kg * 8);
            acc[j][0] = __builtin_amdgcn_mfma_f32_16x16x32_bf16(af, bf, acc[j][0], 0, 0, 0);
        }
    }
#pragma unroll
    for (int j = 0; j < 8; ++j) { acc[j][1] = acc[j][0]; acc[j][2] = acc[j][0]; }

    // ---- phase B: k 128..511 (hE part), 1-deep register prefetch ----
    float4 e0[3], e1[3];
#pragma unroll
    for (int i = 0; i < 3; ++i) {
        const float* p = hE + (node * 48 + 16 * i + ln) * 384 + kg * 8;
        e0[i] = *(const float4*)p;
        e1[i] = *(const float4*)(p + 4);
    }
    for (int ks = 4; ks < 16; ++ks) {
        float4 f0[3], f1[3];
        if (ks < 15) {
#pragma unroll
            for (int i = 0; i < 3; ++i) {
                const float* p = hE + (node * 48 + 16 * i + ln) * 384 + (ks - 3) * 32 + kg * 8;
                f0[i] = *(const float4*)p;
                f1[i] = *(const float4*)(p + 4);
            }
        }
        short8 bf[3];
#pragma unroll
        for (int i = 0; i < 3; ++i) bf[i] = cvt8(e0[i], e1[i]);
#pragma unroll
        for (int j = 0; j < 8; ++j) {
            short8 af = *(const short8*)(w1t + (j * 16 + ln) * 512 + ks * 32 + kg * 8);
#pragma unroll
            for (int i = 0; i < 3; ++i)
                acc[j][i] = __builtin_amdgcn_mfma_f32_16x16x32_bf16(af, bf[i], acc[j][i], 0, 0, 0);
        }
#pragma unroll
        for (int i = 0; i < 3; ++i) { e0[i] = f0[i]; e1[i] = f1[i]; }
    }

    // ---- epilogue 1: gelu(x+b1) -> Hw (row n, 4 consecutive m per lane) ----
#pragma unroll
    for (int j = 0; j < 8; ++j) {
        const float4 bb = *(const float4*)(b1 + j * 16 + 4 * kg);
        const int blk0 = 2 * j + (kg >> 1);
        const int off  = 4 * (kg & 1);
#pragma unroll
        for (int i = 0; i < 3; ++i) {
            const int n = 16 * i + ln;
            short4v p;
            p.x = (short)f2bf(gelu_f(acc[j][i].x + bb.x));
            p.y = (short)f2bf(gelu_f(acc[j][i].y + bb.y));
            p.z = (short)f2bf(gelu_f(acc[j][i].z + bb.z));
            p.w = (short)f2bf(gelu_f(acc[j][i].w + bb.w));
            *(short4v*)&Hw[n * 128 + ((blk0 ^ (n & 7)) * 8) + off] = p;
        }
    }

    // ---- GEMM2 (K=128) and GEMM3 (K=128), W-frags direct from L2 ----
    for (int L = 0; L < 2; ++L) {
        const unsigned short* wt = (L == 0) ? w2t : w3t;
        f32x4 a2[8][3];
#pragma unroll
        for (int j = 0; j < 8; ++j)
#pragma unroll
            for (int i = 0; i < 3; ++i) a2[j][i] = zero4();

#pragma unroll
        for (int c = 0; c < 4; ++c) {
            short8 hb[3];
#pragma unroll
            for (int i = 0; i < 3; ++i) {
                const int n = 16 * i + ln;
                const int blk = (c * 4 + kg) ^ (n & 7);
                hb[i] = *(const short8*)&Hw[n * 128 + blk * 8];
            }
#pragma unroll
            for (int j = 0; j < 8; ++j) {
                short8 af = *(const short8*)(wt + (j * 16 + ln) * 128 + c * 32 + kg * 8);
#pragma unroll
                for (int i = 0; i < 3; ++i)
                    a2[j][i] = __builtin_amdgcn_mfma_f32_16x16x32_bf16(af, hb[i], a2[j][i], 0, 0, 0);
            }
        }

        if (L == 0) {
            // epilogue 2: gelu(x+b2) -> Hw (overwrites H1; same-wave DS is in-order)
#pragma unroll
            for (int j = 0; j < 8; ++j) {
                const float4 bb = *(const float4*)(b2 + j * 16 + 4 * kg);
                const int blk0 = 2 * j + (kg >> 1);
                const int off  = 4 * (kg & 1);
#pragma unroll
                for (int i = 0; i < 3; ++i) {
                    const int n = 16 * i + ln;
                    short4v p;
                    p.x = (short)f2bf(gelu_f(a2[j][i].x + bb.x));
                    p.y = (short)f2bf(gelu_f(a2[j][i].y + bb.y));
                    p.z = (short)f2bf(gelu_f(a2[j][i].z + bb.z));
                    p.w = (short)f2bf(gelu_f(a2[j][i].w + bb.w));
                    *(short4v*)&Hw[n * 128 + ((blk0 ^ (n & 7)) * 8) + off] = p;
                }
            }
        } else {
            // epilogue 3: dh[node][m] = (1/30) * sum_n mask[n] * (x + b3[m])
            float mk[3];
#pragma unroll
            for (int i = 0; i < 3; ++i) mk[i] = mAtt[node * 48 + 16 * i + ln];
#pragma unroll
            for (int j = 0; j < 8; ++j) {
                const float4 bb = *(const float4*)(b3 + j * 16 + 4 * kg);
                float s0 = 0.f, s1 = 0.f, s2 = 0.f, s3 = 0.f;
#pragma unroll
                for (int i = 0; i < 3; ++i) {
                    s0 += (a2[j][i].x + bb.x) * mk[i];
                    s1 += (a2[j][i].y + bb.y) * mk[i];
                    s2 += (a2[j][i].z + bb.z) * mk[i];
                    s3 += (a2[j][i].w + bb.w) * mk[i];
                }
#pragma unroll
                for (int off = 1; off < 16; off <<= 1) {
                    s0 += __shfl_xor(s0, off, 64);
                    s1 += __shfl_xor(s1, off, 64);
                    s2 += __shfl_xor(s2, off, 64);
                    s3 += __shfl_xor(s3, off, 64);
                }
                if (ln == 0) {
                    float4 o;
                    o.x = s0 * RSCALE; o.y = s1 * RSCALE;
                    o.z = s2 * RSCALE; o.w = s3 * RSCALE;
                    *(float4*)&dh[node * 128 + j * 16 + 4 * kg] = o;
                }
            }
        }
    }
}

// ---------------------------------------------------------------------------
// Kernel 2: per-node rezero+LN1 -> FFN(128->512->128) -> rezero+LN2 -> mask
// 16 nodes per WG, 512 WGs, fp32 VALU.  (unchanged from R1 — passed)
// ---------------------------------------------------------------------------
__global__ __launch_bounds__(256, 2) void node_ffn(
    const float* __restrict__ hV, const float* __restrict__ dh,
    const float* __restrict__ maskV,
    const float* __restrict__ g1, const float* __restrict__ be1,
    const float* __restrict__ g2, const float* __restrict__ be2,
    const float* __restrict__ Wi, const float* __restrict__ bi,
    const float* __restrict__ Wo, const float* __restrict__ bo,
    const float* __restrict__ alphap, float* __restrict__ out)
{
    __shared__ float hbuf[16 * 132];
    __shared__ float hidb[16 * 516];
    __shared__ float obuf[16 * 132];

    const int tid = threadIdx.x;
    const float al = alphap[0];
    const int nb = blockIdx.x * 16;

    {
        const int m = tid >> 4, s = tid & 15;
        const int i0 = s * 8;
        const int base = (nb + m) * 128 + i0;
        float x[8];
        {
            float4 a0 = *(const float4*)(dh + base);
            float4 a1 = *(const float4*)(dh + base + 4);
            float4 v0 = *(const float4*)(hV + base);
            float4 v1 = *(const float4*)(hV + base + 4);
            x[0] = v0.x + al * a0.x; x[1] = v0.y + al * a0.y;
            x[2] = v0.z + al * a0.z; x[3] = v0.w + al * a0.w;
            x[4] = v1.x + al * a1.x; x[5] = v1.y + al * a1.y;
            x[6] = v1.z + al * a1.z; x[7] = v1.w + al * a1.w;
        }
        float sm = 0.f;
#pragma unroll
        for (int q = 0; q < 8; ++q) sm += x[q];
#pragma unroll
        for (int off = 1; off < 16; off <<= 1) sm += __shfl_xor(sm, off, 64);
        const float mu = sm * (1.0f / 128.0f);
        float vs = 0.f;
#pragma unroll
        for (int q = 0; q < 8; ++q) { float d = x[q] - mu; vs += d * d; }
#pragma unroll
        for (int off = 1; off < 16; off <<= 1) vs += __shfl_xor(vs, off, 64);
        const float rs = rsqrtf(vs * (1.0f / 128.0f) + LN_EPS);
#pragma unroll
        for (int q = 0; q < 8; ++q)
            hbuf[m * 132 + i0 + q] = (x[q] - mu) * rs * g1[i0 + q] + be1[i0 + q];
    }
    __syncthreads();

    {
        const int jg = tid & 127, mhh = tid >> 7;
        const int j4 = jg * 4;
        float acc[8][4];
#pragma unroll
        for (int mm = 0; mm < 8; ++mm)
#pragma unroll
            for (int jj = 0; jj < 4; ++jj) acc[mm][jj] = 0.f;
        for (int i0 = 0; i0 < 128; i0 += 4) {
            float4 w0 = *(const float4*)(Wi + (i0 + 0) * 512 + j4);
            float4 w1 = *(const float4*)(Wi + (i0 + 1) * 512 + j4);
            float4 w2 = *(const float4*)(Wi + (i0 + 2) * 512 + j4);
            float4 w3 = *(const float4*)(Wi + (i0 + 3) * 512 + j4);
#pragma unroll
            for (int mm = 0; mm < 8; ++mm) {
                float4 h4 = *(const float4*)&hbuf[(mhh * 8 + mm) * 132 + i0];
                acc[mm][0] += h4.x * w0.x + h4.y * w1.x + h4.z * w2.x + h4.w * w3.x;
                acc[mm][1] += h4.x * w0.y + h4.y * w1.y + h4.z * w2.y + h4.w * w3.y;
                acc[mm][2] += h4.x * w0.z + h4.y * w1.z + h4.z * w2.z + h4.w * w3.z;
                acc[mm][3] += h4.x * w0.w + h4.y * w1.w + h4.z * w2.w + h4.w * w3.w;
            }
        }
        float4 bb = *(const float4*)(bi + j4);
#pragma unroll
        for (int mm = 0; mm < 8; ++mm) {
            float4 o;
            o.x = gelu_f(acc[mm][0] + bb.x);
            o.y = gelu_f(acc[mm][1] + bb.y);
            o.z = gelu_f(acc[mm][2] + bb.z);
            o.w = gelu_f(acc[mm][3] + bb.w);
            *(float4*)&hidb[(mhh * 8 + mm) * 516 + j4] = o;
        }
    }
    __syncthreads();

    {
        const int m = tid >> 4;
        const int n8 = (tid & 15) * 8;
        float4 r0, r1;
        r0.x = r0.y = r0.z = r0.w = 0.f;
        r1.x = r1.y = r1.z = r1.w = 0.f;
        for (int j0 = 0; j0 < 512; j0 += 4) {
            float4 hh = *(const float4*)&hidb[m * 516 + j0];
            float hq[4] = {hh.x, hh.y, hh.z, hh.w};
#pragma unroll
            for (int jj = 0; jj < 4; ++jj) {
                float4 w0 = *(const float4*)(Wo + (j0 + jj) * 128 + n8);
                float4 w1 = *(const float4*)(Wo + (j0 + jj) * 128 + n8 + 4);
                r0.x += hq[jj] * w0.x; r0.y += hq[jj] * w0.y;
                r0.z += hq[jj] * w0.z; r0.w += hq[jj] * w0.w;
                r1.x += hq[jj] * w1.x; r1.y += hq[jj] * w1.y;
                r1.z += hq[jj] * w1.z; r1.w += hq[jj] * w1.w;
            }
        }
        float4 q0 = *(const float4*)(bo + n8);
        float4 q1 = *(const float4*)(bo + n8 + 4);
        r0.x += q0.x; r0.y += q0.y; r0.z += q0.z; r0.w += q0.w;
        r1.x += q1.x; r1.y += q1.y; r1.z += q1.z; r1.w += q1.w;
        *(float4*)&obuf[m * 132 + n8]     = r0;
        *(float4*)&obuf[m * 132 + n8 + 4] = r1;
    }
    __syncthreads();

    {
        const int m = tid >> 4, s = tid & 15;
        const int i0 = s * 8;
        float x[8];
#pragma unroll
        for (int q = 0; q < 8; ++q)
            x[q] = hbuf[m * 132 + i0 + q] + al * obuf[m * 132 + i0 + q];
        float sm = 0.f;
#pragma unroll
        for (int q = 0; q < 8; ++q) sm += x[q];
#pragma unroll
        for (int off = 1; off < 16; off <<= 1) sm += __shfl_xor(sm, off, 64);
        const float mu = sm * (1.0f / 128.0f);
        float vs = 0.f;
#pragma unroll
        for (int q = 0; q < 8; ++q) { float d = x[q] - mu; vs += d * d; }
#pragma unroll
        for (int off = 1; off < 16; off <<= 1) vs += __shfl_xor(vs, off, 64);
        const float rs = rsqrtf(vs * (1.0f / 128.0f) + LN_EPS);
        const float mk = maskV[nb + m];
        float y[8];
#pragma unroll
        for (int q = 0; q < 8; ++q)
            y[q] = ((x[q] - mu) * rs * g2[i0 + q] + be2[i0 + q]) * mk;
        float4 o0, o1;
        o0.x = y[0]; o0.y = y[1]; o0.z = y[2]; o0.w = y[3];
        o1.x = y[4]; o1.y = y[5]; o1.z = y[6]; o1.w = y[7];
        const int base = (nb + m) * 128 + i0;
        *(float4*)(out + base)     = o0;
        *(float4*)(out + base + 4) = o1;
    }
}

// ---------------------------------------------------------------------------
extern "C" void kernel_launch(void* const* d_in, const int* in_sizes, int n_in,
                              void* d_out, int out_size, void* d_ws, size_t ws_size,
                              hipStream_t stream)
{
    const float* hV  = (const float*)d_in[0];
    const float* hE  = (const float*)d_in[1];
    const float* mV  = (const float*)d_in[2];
    const float* mA  = (const float*)d_in[3];
    const float* W1  = (const float*)d_in[4];
    const float* b1  = (const float*)d_in[5];
    const float* W2  = (const float*)d_in[6];
    const float* b2  = (const float*)d_in[7];
    const float* W3  = (const float*)d_in[8];
    const float* b3  = (const float*)d_in[9];
    const float* g1  = (const float*)d_in[10];
    const float* be1 = (const float*)d_in[11];
    const float* g2  = (const float*)d_in[12];
    const float* be2 = (const float*)d_in[13];
    const float* Wi  = (const float*)d_in[14];
    const float* bi  = (const float*)d_in[15];
    const float* Wo  = (const float*)d_in[16];
    const float* bo  = (const float*)d_in[17];
    const float* al  = (const float*)d_in[18];
    float* out = (float*)d_out;

    float* dh = (float*)d_ws;
    unsigned short* w1t = (unsigned short*)((char*)d_ws + (size_t)4194304);
    unsigned short* w2t = w1t + 65536;
    unsigned short* w3t = w2t + 16384;

    prep_w  <<<384,  256, 0, stream>>>(W1, W2, W3, w1t, w2t, w3t);
    edge_mlp<<<2048, 256, 0, stream>>>(hV, hE, mA, w1t, w2t, w3t, b1, b2, b3, dh);
    node_ffn<<<512,  256, 0, stream>>>(hV, dh, mV, g1, be1, g2, be2, Wi, bi, Wo, bo, al, out);
}

// Round 3
// 1028.023 us; speedup vs baseline: 1.0373x; 1.0373x over previous
//
#include <hip/hip_runtime.h>

#define LN_EPS 1e-5f
#define RSCALE (1.0f / 30.0f)

typedef short short8  __attribute__((ext_vector_type(8)));
typedef short short4v __attribute__((ext_vector_type(4)));
typedef float f32x4   __attribute__((ext_vector_type(4)));

__device__ __forceinline__ unsigned short f2bf(float f) {
    unsigned u = __builtin_bit_cast(unsigned, f);
    u = u + 0x7FFFu + ((u >> 16) & 1u);   // round-to-nearest-even
    return (unsigned short)(u >> 16);
}

__device__ __forceinline__ float gelu_f(float x) {
    float u  = 0.7978845608028654f * (x + 0.044715f * x * x * x);
    float e  = __expf(-2.0f * fabsf(u));
    float t  = 1.0f - 2.0f * e / (1.0f + e);
    return 0.5f * x * (1.0f + copysignf(t, u));
}

__device__ __forceinline__ short8 cvt8(float4 a, float4 b) {
    short8 r;
    r[0] = (short)f2bf(a.x); r[1] = (short)f2bf(a.y);
    r[2] = (short)f2bf(a.z); r[3] = (short)f2bf(a.w);
    r[4] = (short)f2bf(b.x); r[5] = (short)f2bf(b.y);
    r[6] = (short)f2bf(b.z); r[7] = (short)f2bf(b.w);
    return r;
}

__device__ __forceinline__ f32x4 zero4() {
    f32x4 v; v.x = 0.f; v.y = 0.f; v.z = 0.f; v.w = 0.f; return v;
}

// async global -> LDS, 16 B per lane (hardware queue, no VGPR round-trip)
__device__ __forceinline__ void gl_lds16(const float* g, float* l) {
    __builtin_amdgcn_global_load_lds(
        (const __attribute__((address_space(1))) void*)g,
        (__attribute__((address_space(3))) void*)l, 16, 0, 0);
}

// ---------------------------------------------------------------------------
// Kernel 0: convert W1/W2/W3 (fp32 [in][out]) -> bf16 transposed [out][in]
// ---------------------------------------------------------------------------
__global__ __launch_bounds__(256) void prep_w(
    const float* __restrict__ W1, const float* __restrict__ W2,
    const float* __restrict__ W3,
    unsigned short* __restrict__ w1t, unsigned short* __restrict__ w2t,
    unsigned short* __restrict__ w3t)
{
    int t = blockIdx.x * 256 + threadIdx.x;
    if (t < 65536) {                       // W1: [512][128] -> w1t [128][512]
        int m = t & 127, k = t >> 7;
        w1t[m * 512 + k] = f2bf(W1[k * 128 + m]);
    } else if (t < 81920) {                // W2
        int u = t - 65536, m = u & 127, k = u >> 7;
        w2t[m * 128 + k] = f2bf(W2[k * 128 + m]);
    } else if (t < 98304) {                // W3
        int u = t - 81920, m = u & 127, k = u >> 7;
        w3t[m * 128 + k] = f2bf(W3[k * 128 + m]);
    }
}

// ---------------------------------------------------------------------------
// Kernel 1 (v3): fused edge MLP, m97-style async staging.
// WG = 256 thr = 4 waves = 2 nodes. Wave (nl = wv>>1, mh = wv&1) handles
// node nl's 3 N-tiles x 4 M-tiles (neuron half mh). 16x16x32 bf16 MFMA.
//  - hE streamed via global_load_lds (12 KB/chunk of K=32, 1 buf, 2-barrier
//    loop): hardware async queue keeps the whole chunk in flight -> no
//    per-load vmcnt serialization (R2's failure mode).
//  - XOR swizzle applied on the GLOBAL address (LDS side must stay
//    lane-contiguous for global_load_lds): LDS(row,u) = G(row, u^(row&7)).
//  - hV K-range (0..127): per-node dedup, 8 hoisted broadcast loads.
//  - W fragments direct from L2 (128 KB w1t shared by all WGs).
// ---------------------------------------------------------------------------
__global__ __launch_bounds__(256, 3) void edge_mlp(
    const float* __restrict__ hV, const float* __restrict__ hE,
    const float* __restrict__ mAtt,
    const unsigned short* __restrict__ w1t, const unsigned short* __restrict__ w2t,
    const unsigned short* __restrict__ w3t,
    const float* __restrict__ b1, const float* __restrict__ b2,
    const float* __restrict__ b3, float* __restrict__ dh)
{
    __shared__ __align__(16) float Abuf[96 * 32];      // 12 KB staged hE chunk
    __shared__ __align__(16) short Hs[2][48 * 128];    // 2 x 12 KB H slabs
    __shared__ float mb[96];

    const int tid  = threadIdx.x;
    const int wv   = tid >> 6;
    const int lane = tid & 63;
    const int ln   = lane & 15;
    const int kg   = lane >> 4;
    const int nl   = wv >> 1;              // node within WG
    const int mh   = wv & 1;               // neuron half
    const int node = blockIdx.x * 2 + nl;
    const int base_row = blockIdx.x * 96;
    short* Hw = &Hs[nl][0];

    if (tid < 96) mb[tid] = mAtt[base_row + tid];

    f32x4 acc[4][3];

    // ---- phase A: k 0..127 (hV, identical across the node's 48 rows) ----
#pragma unroll
    for (int j = 0; j < 4; ++j) acc[j][0] = zero4();
    {
        float4 hv[8];
#pragma unroll
        for (int ks = 0; ks < 4; ++ks) {
            const float* p = hV + node * 128 + ks * 32 + kg * 8;
            hv[2 * ks]     = *(const float4*)p;
            hv[2 * ks + 1] = *(const float4*)(p + 4);
        }
#pragma unroll
        for (int ks = 0; ks < 4; ++ks) {
            short8 bfv = cvt8(hv[2 * ks], hv[2 * ks + 1]);
#pragma unroll
            for (int j = 0; j < 4; ++j) {
                const int m = (mh * 4 + j) * 16 + ln;
                short8 af = *(const short8*)(w1t + (size_t)m * 512 + ks * 32 + kg * 8);
                acc[j][0] = __builtin_amdgcn_mfma_f32_16x16x32_bf16(af, bfv, acc[j][0], 0, 0, 0);
            }
        }
    }
#pragma unroll
    for (int j = 0; j < 4; ++j) { acc[j][1] = acc[j][0]; acc[j][2] = acc[j][0]; }

    // ---- main loop: hE K-chunks of 32 (12 chunks), 2-barrier structure ----
    for (int c = 0; c < 12; ++c) {
        if (c) __syncthreads();            // prev compute done before overwrite
#pragma unroll
        for (int q = 0; q < 3; ++q) {
            const int o   = q * 256 + tid;         // slot 0..767
            const int row = o >> 3, u = o & 7;
            const int ku  = u ^ (row & 7);         // global-address swizzle
            const float* g = hE + (size_t)(base_row + row) * 384 + c * 32 + ku * 4;
            gl_lds16(g, &Abuf[o * 4]);
        }
        __syncthreads();                   // drains vmcnt -> chunk ready

        short8 bf[3];
#pragma unroll
        for (int i = 0; i < 3; ++i) {
            const int row = nl * 48 + 16 * i + ln;
            const int u0 = (2 * kg)     ^ (row & 7);
            const int u1 = (2 * kg + 1) ^ (row & 7);
            float4 x0 = *(const float4*)&Abuf[row * 32 + u0 * 4];
            float4 x1 = *(const float4*)&Abuf[row * 32 + u1 * 4];
            bf[i] = cvt8(x0, x1);
        }
#pragma unroll
        for (int j = 0; j < 4; ++j) {
            const int m = (mh * 4 + j) * 16 + ln;
            short8 af = *(const short8*)(w1t + (size_t)m * 512 + 128 + c * 32 + kg * 8);
#pragma unroll
            for (int i = 0; i < 3; ++i)
                acc[j][i] = __builtin_amdgcn_mfma_f32_16x16x32_bf16(af, bf[i], acc[j][i], 0, 0, 0);
        }
    }
    __syncthreads();

    // ---- epilogue 1: gelu(x+b1) -> Hw ----
#pragma unroll
    for (int j = 0; j < 4; ++j) {
        const int J  = mh * 4 + j;
        const float4 bb = *(const float4*)(b1 + J * 16 + 4 * kg);
        const int blk0 = 2 * J + (kg >> 1);
        const int off  = 4 * (kg & 1);
#pragma unroll
        for (int i = 0; i < 3; ++i) {
            const int n = 16 * i + ln;
            short4v p;
            p.x = (short)f2bf(gelu_f(acc[j][i].x + bb.x));
            p.y = (short)f2bf(gelu_f(acc[j][i].y + bb.y));
            p.z = (short)f2bf(gelu_f(acc[j][i].z + bb.z));
            p.w = (short)f2bf(gelu_f(acc[j][i].w + bb.w));
            *(short4v*)&Hw[n * 128 + ((blk0 ^ (n & 7)) * 8) + off] = p;
        }
    }
    __syncthreads();

    // ---- GEMM2 (K=128) then GEMM3 (K=128) ----
    for (int L = 0; L < 2; ++L) {
        const unsigned short* wt = (L == 0) ? w2t : w3t;
        f32x4 a2[4][3];
#pragma unroll
        for (int j = 0; j < 4; ++j)
#pragma unroll
            for (int i = 0; i < 3; ++i) a2[j][i] = zero4();

#pragma unroll
        for (int c2 = 0; c2 < 4; ++c2) {
            short8 hb[3];
#pragma unroll
            for (int i = 0; i < 3; ++i) {
                const int n = 16 * i + ln;
                const int blk = (c2 * 4 + kg) ^ (n & 7);
                hb[i] = *(const short8*)&Hw[n * 128 + blk * 8];
            }
#pragma unroll
            for (int j = 0; j < 4; ++j) {
                const int m = (mh * 4 + j) * 16 + ln;
                short8 af = *(const short8*)(wt + (size_t)m * 128 + c2 * 32 + kg * 8);
#pragma unroll
                for (int i = 0; i < 3; ++i)
                    a2[j][i] = __builtin_amdgcn_mfma_f32_16x16x32_bf16(af, hb[i], a2[j][i], 0, 0, 0);
            }
        }
        __syncthreads();                   // slab reads done

        if (L == 0) {
            // epilogue 2: gelu(x+b2) -> Hw (overwrite)
#pragma unroll
            for (int j = 0; j < 4; ++j) {
                const int J  = mh * 4 + j;
                const float4 bb = *(const float4*)(b2 + J * 16 + 4 * kg);
                const int blk0 = 2 * J + (kg >> 1);
                const int off  = 4 * (kg & 1);
#pragma unroll
                for (int i = 0; i < 3; ++i) {
                    const int n = 16 * i + ln;
                    short4v p;
                    p.x = (short)f2bf(gelu_f(a2[j][i].x + bb.x));
                    p.y = (short)f2bf(gelu_f(a2[j][i].y + bb.y));
                    p.z = (short)f2bf(gelu_f(a2[j][i].z + bb.z));
                    p.w = (short)f2bf(gelu_f(a2[j][i].w + bb.w));
                    *(short4v*)&Hw[n * 128 + ((blk0 ^ (n & 7)) * 8) + off] = p;
                }
            }
            __syncthreads();
        } else {
            // epilogue 3: dh[node][m] = (1/30) * sum_n mask[n] * (x + b3[m])
            float mk[3];
#pragma unroll
            for (int i = 0; i < 3; ++i) mk[i] = mb[nl * 48 + 16 * i + ln];
#pragma unroll
            for (int j = 0; j < 4; ++j) {
                const int J = mh * 4 + j;
                const float4 bb = *(const float4*)(b3 + J * 16 + 4 * kg);
                float s0 = 0.f, s1 = 0.f, s2 = 0.f, s3 = 0.f;
#pragma unroll
                for (int i = 0; i < 3; ++i) {
                    s0 += (a2[j][i].x + bb.x) * mk[i];
                    s1 += (a2[j][i].y + bb.y) * mk[i];
                    s2 += (a2[j][i].z + bb.z) * mk[i];
                    s3 += (a2[j][i].w + bb.w) * mk[i];
                }
#pragma unroll
                for (int off = 1; off < 16; off <<= 1) {
                    s0 += __shfl_xor(s0, off, 64);
                    s1 += __shfl_xor(s1, off, 64);
                    s2 += __shfl_xor(s2, off, 64);
                    s3 += __shfl_xor(s3, off, 64);
                }
                if (ln == 0) {
                    float4 o;
                    o.x = s0 * RSCALE; o.y = s1 * RSCALE;
                    o.z = s2 * RSCALE; o.w = s3 * RSCALE;
                    *(float4*)&dh[node * 128 + J * 16 + 4 * kg] = o;
                }
            }
        }
    }
}

// ---------------------------------------------------------------------------
// Kernel 2: per-node rezero+LN1 -> FFN(128->512->128) -> rezero+LN2 -> mask
// (unchanged from R1/R2 — passed; optimize only if counters say it matters)
// ---------------------------------------------------------------------------
__global__ __launch_bounds__(256, 2) void node_ffn(
    const float* __restrict__ hV, const float* __restrict__ dh,
    const float* __restrict__ maskV,
    const float* __restrict__ g1, const float* __restrict__ be1,
    const float* __restrict__ g2, const float* __restrict__ be2,
    const float* __restrict__ Wi, const float* __restrict__ bi,
    const float* __restrict__ Wo, const float* __restrict__ bo,
    const float* __restrict__ alphap, float* __restrict__ out)
{
    __shared__ float hbuf[16 * 132];
    __shared__ float hidb[16 * 516];
    __shared__ float obuf[16 * 132];

    const int tid = threadIdx.x;
    const float al = alphap[0];
    const int nb = blockIdx.x * 16;

    {
        const int m = tid >> 4, s = tid & 15;
        const int i0 = s * 8;
        const int base = (nb + m) * 128 + i0;
        float x[8];
        {
            float4 a0 = *(const float4*)(dh + base);
            float4 a1 = *(const float4*)(dh + base + 4);
            float4 v0 = *(const float4*)(hV + base);
            float4 v1 = *(const float4*)(hV + base + 4);
            x[0] = v0.x + al * a0.x; x[1] = v0.y + al * a0.y;
            x[2] = v0.z + al * a0.z; x[3] = v0.w + al * a0.w;
            x[4] = v1.x + al * a1.x; x[5] = v1.y + al * a1.y;
            x[6] = v1.z + al * a1.z; x[7] = v1.w + al * a1.w;
        }
        float sm = 0.f;
#pragma unroll
        for (int q = 0; q < 8; ++q) sm += x[q];
#pragma unroll
        for (int off = 1; off < 16; off <<= 1) sm += __shfl_xor(sm, off, 64);
        const float mu = sm * (1.0f / 128.0f);
        float vs = 0.f;
#pragma unroll
        for (int q = 0; q < 8; ++q) { float d = x[q] - mu; vs += d * d; }
#pragma unroll
        for (int off = 1; off < 16; off <<= 1) vs += __shfl_xor(vs, off, 64);
        const float rs = rsqrtf(vs * (1.0f / 128.0f) + LN_EPS);
#pragma unroll
        for (int q = 0; q < 8; ++q)
            hbuf[m * 132 + i0 + q] = (x[q] - mu) * rs * g1[i0 + q] + be1[i0 + q];
    }
    __syncthreads();

    {
        const int jg = tid & 127, mhh = tid >> 7;
        const int j4 = jg * 4;
        float acc[8][4];
#pragma unroll
        for (int mm = 0; mm < 8; ++mm)
#pragma unroll
            for (int jj = 0; jj < 4; ++jj) acc[mm][jj] = 0.f;
        for (int i0 = 0; i0 < 128; i0 += 4) {
            float4 w0 = *(const float4*)(Wi + (i0 + 0) * 512 + j4);
            float4 w1 = *(const float4*)(Wi + (i0 + 1) * 512 + j4);
            float4 w2 = *(const float4*)(Wi + (i0 + 2) * 512 + j4);
            float4 w3 = *(const float4*)(Wi + (i0 + 3) * 512 + j4);
#pragma unroll
            for (int mm = 0; mm < 8; ++mm) {
                float4 h4 = *(const float4*)&hbuf[(mhh * 8 + mm) * 132 + i0];
                acc[mm][0] += h4.x * w0.x + h4.y * w1.x + h4.z * w2.x + h4.w * w3.x;
                acc[mm][1] += h4.x * w0.y + h4.y * w1.y + h4.z * w2.y + h4.w * w3.y;
                acc[mm][2] += h4.x * w0.z + h4.y * w1.z + h4.z * w2.z + h4.w * w3.z;
                acc[mm][3] += h4.x * w0.w + h4.y * w1.w + h4.z * w2.w + h4.w * w3.w;
            }
        }
        float4 bb = *(const float4*)(bi + j4);
#pragma unroll
        for (int mm = 0; mm < 8; ++mm) {
            float4 o;
            o.x = gelu_f(acc[mm][0] + bb.x);
            o.y = gelu_f(acc[mm][1] + bb.y);
            o.z = gelu_f(acc[mm][2] + bb.z);
            o.w = gelu_f(acc[mm][3] + bb.w);
            *(float4*)&hidb[(mhh * 8 + mm) * 516 + j4] = o;
        }
    }
    __syncthreads();

    {
        const int m = tid >> 4;
        const int n8 = (tid & 15) * 8;
        float4 r0, r1;
        r0.x = r0.y = r0.z = r0.w = 0.f;
        r1.x = r1.y = r1.z = r1.w = 0.f;
        for (int j0 = 0; j0 < 512; j0 += 4) {
            float4 hh = *(const float4*)&hidb[m * 516 + j0];
            float hq[4] = {hh.x, hh.y, hh.z, hh.w};
#pragma unroll
            for (int jj = 0; jj < 4; ++jj) {
                float4 w0 = *(const float4*)(Wo + (j0 + jj) * 128 + n8);
                float4 w1 = *(const float4*)(Wo + (j0 + jj) * 128 + n8 + 4);
                r0.x += hq[jj] * w0.x; r0.y += hq[jj] * w0.y;
                r0.z += hq[jj] * w0.z; r0.w += hq[jj] * w0.w;
                r1.x += hq[jj] * w1.x; r1.y += hq[jj] * w1.y;
                r1.z += hq[jj] * w1.z; r1.w += hq[jj] * w1.w;
            }
        }
        float4 q0 = *(const float4*)(bo + n8);
        float4 q1 = *(const float4*)(bo + n8 + 4);
        r0.x += q0.x; r0.y += q0.y; r0.z += q0.z; r0.w += q0.w;
        r1.x += q1.x; r1.y += q1.y; r1.z += q1.z; r1.w += q1.w;
        *(float4*)&obuf[m * 132 + n8]     = r0;
        *(float4*)&obuf[m * 132 + n8 + 4] = r1;
    }
    __syncthreads();

    {
        const int m = tid >> 4, s = tid & 15;
        const int i0 = s * 8;
        float x[8];
#pragma unroll
        for (int q = 0; q < 8; ++q)
            x[q] = hbuf[m * 132 + i0 + q] + al * obuf[m * 132 + i0 + q];
        float sm = 0.f;
#pragma unroll
        for (int q = 0; q < 8; ++q) sm += x[q];
#pragma unroll
        for (int off = 1; off < 16; off <<= 1) sm += __shfl_xor(sm, off, 64);
        const float mu = sm * (1.0f / 128.0f);
        float vs = 0.f;
#pragma unroll
        for (int q = 0; q < 8; ++q) { float d = x[q] - mu; vs += d * d; }
#pragma unroll
        for (int off = 1; off < 16; off <<= 1) vs += __shfl_xor(vs, off, 64);
        const float rs = rsqrtf(vs * (1.0f / 128.0f) + LN_EPS);
        const float mk = maskV[nb + m];
        float y[8];
#pragma unroll
        for (int q = 0; q < 8; ++q)
            y[q] = ((x[q] - mu) * rs * g2[i0 + q] + be2[i0 + q]) * mk;
        float4 o0, o1;
        o0.x = y[0]; o0.y = y[1]; o0.z = y[2]; o0.w = y[3];
        o1.x = y[4]; o1.y = y[5]; o1.z = y[6]; o1.w = y[7];
        const int base = (nb + m) * 128 + i0;
        *(float4*)(out + base)     = o0;
        *(float4*)(out + base + 4) = o1;
    }
}

// ---------------------------------------------------------------------------
extern "C" void kernel_launch(void* const* d_in, const int* in_sizes, int n_in,
                              void* d_out, int out_size, void* d_ws, size_t ws_size,
                              hipStream_t stream)
{
    const float* hV  = (const float*)d_in[0];
    const float* hE  = (const float*)d_in[1];
    const float* mV  = (const float*)d_in[2];
    const float* mA  = (const float*)d_in[3];
    const float* W1  = (const float*)d_in[4];
    const float* b1  = (const float*)d_in[5];
    const float* W2  = (const float*)d_in[6];
    const float* b2  = (const float*)d_in[7];
    const float* W3  = (const float*)d_in[8];
    const float* b3  = (const float*)d_in[9];
    const float* g1  = (const float*)d_in[10];
    const float* be1 = (const float*)d_in[11];
    const float* g2  = (const float*)d_in[12];
    const float* be2 = (const float*)d_in[13];
    const float* Wi  = (const float*)d_in[14];
    const float* bi  = (const float*)d_in[15];
    const float* Wo  = (const float*)d_in[16];
    const float* bo  = (const float*)d_in[17];
    const float* al  = (const float*)d_in[18];
    float* out = (float*)d_out;

    float* dh = (float*)d_ws;
    unsigned short* w1t = (unsigned short*)((char*)d_ws + (size_t)4194304);
    unsigned short* w2t = w1t + 65536;
    unsigned short* w3t = w2t + 16384;

    prep_w  <<<384,  256, 0, stream>>>(W1, W2, W3, w1t, w2t, w3t);
    edge_mlp<<<4096, 256, 0, stream>>>(hV, hE, mA, w1t, w2t, w3t, b1, b2, b3, dh);
    node_ffn<<<512,  256, 0, stream>>>(hV, dh, mV, g1, be1, g2, be2, Wi, bi, Wo, bo, al, out);
}